// Round 1
// baseline (334.251 us; speedup 1.0000x reference)
//
#include <hip/hip_runtime.h>

#define IMG 224
#define PATCHSZ 16
#define CHN 3
#define DDIM 768
#define ROWN 14
#define NPATCH 196
#define PDIM 768
#define BATCH 32

#define DTILE 256
#define KCHUNK 64

// Kernel 1: x[32][3][224][224] -> P[196][32][768]
// k = ch*256 + py*16 + px  (matches torch crop+flatten order)
__global__ void extract_patches_kernel(const float* __restrict__ x,
                                       float* __restrict__ P) {
    int i = blockIdx.x * blockDim.x + threadIdx.x;
    if (i >= NPATCH * BATCH * PDIM) return;
    int k  = i % PDIM;
    int nb = i / PDIM;
    int b  = nb % BATCH;
    int n  = nb / BATCH;
    int ch = k >> 8;
    int py = (k >> 4) & 15;
    int px = k & 15;
    int r = n / ROWN, c = n % ROWN;
    int y = r * PATCHSZ + py;
    int xx = c * PATCHSZ + px;
    P[i] = x[(((size_t)b * CHN + ch) * IMG + y) * IMG + xx];
}

// Kernel 2: per patch n: out[:,n,:] = P[n] (32x768) * W[n] (768x768) + bias[n]
// grid = 196 * 3 blocks; block tile = 32 batches x 256 d-cols
// per thread: 8 batches x 4 d-cols
__global__ __launch_bounds__(256) void patch_gemm_kernel(
    const float* __restrict__ P,    // [196][32][768]
    const float* __restrict__ W,    // [196][768][768]
    const float* __restrict__ bias, // [196][768]
    float* __restrict__ out)        // [32][196][768]
{
    __shared__ float ap[KCHUNK][BATCH];  // transposed chunk [k][b], 8 KB

    int blk  = blockIdx.x;
    int n    = blk / 3;
    int dblk = blk % 3;
    int tid  = threadIdx.x;
    int dg   = tid & 63;       // d-group: 64 per block
    int bg   = tid >> 6;       // wave-uniform batch group 0..3
    int b0   = bg * 8;
    int d    = dblk * DTILE + dg * 4;

    const float* Wn = W + (size_t)n * PDIM * DDIM + d;
    const float* Pn = P + (size_t)n * BATCH * PDIM;

    float acc[8][4];
#pragma unroll
    for (int i = 0; i < 8; ++i)
#pragma unroll
        for (int j = 0; j < 4; ++j) acc[i][j] = 0.f;

    // staging mapping: thread -> (row b, 8 consecutive k)
    int sb = tid >> 3;          // 0..31
    int sk = (tid & 7) * 8;     // 0,8,...,56

    for (int kc = 0; kc < PDIM; kc += KCHUNK) {
        const float4* src =
            reinterpret_cast<const float4*>(Pn + (size_t)sb * PDIM + kc + sk);
        float4 v0 = src[0];
        float4 v1 = src[1];
        __syncthreads();   // previous chunk's compute done before overwrite
        ap[sk + 0][sb] = v0.x;
        ap[sk + 1][sb] = v0.y;
        ap[sk + 2][sb] = v0.z;
        ap[sk + 3][sb] = v0.w;
        ap[sk + 4][sb] = v1.x;
        ap[sk + 5][sb] = v1.y;
        ap[sk + 6][sb] = v1.z;
        ap[sk + 7][sb] = v1.w;
        __syncthreads();

#pragma unroll 8
        for (int kk = 0; kk < KCHUNK; ++kk) {
            float4 w = *reinterpret_cast<const float4*>(
                Wn + (size_t)(kc + kk) * DDIM);
            // broadcast reads (wave-uniform address), 16B-aligned
            float4 p01 = *reinterpret_cast<const float4*>(&ap[kk][b0]);
            float4 p23 = *reinterpret_cast<const float4*>(&ap[kk][b0 + 4]);
            float pv[8] = {p01.x, p01.y, p01.z, p01.w,
                           p23.x, p23.y, p23.z, p23.w};
#pragma unroll
            for (int i = 0; i < 8; ++i) {
                acc[i][0] += pv[i] * w.x;
                acc[i][1] += pv[i] * w.y;
                acc[i][2] += pv[i] * w.z;
                acc[i][3] += pv[i] * w.w;
            }
        }
    }

    float4 bv = *reinterpret_cast<const float4*>(bias + (size_t)n * DDIM + d);
#pragma unroll
    for (int i = 0; i < 8; ++i) {
        int b = b0 + i;
        float4 o;
        o.x = acc[i][0] + bv.x;
        o.y = acc[i][1] + bv.y;
        o.z = acc[i][2] + bv.z;
        o.w = acc[i][3] + bv.w;
        *reinterpret_cast<float4*>(
            out + ((size_t)b * NPATCH + n) * DDIM + d) = o;
    }
}

extern "C" void kernel_launch(void* const* d_in, const int* in_sizes, int n_in,
                              void* d_out, int out_size, void* d_ws, size_t ws_size,
                              hipStream_t stream) {
    const float* x    = (const float*)d_in[0];
    const float* W    = (const float*)d_in[1];
    const float* bias = (const float*)d_in[2];
    float* out = (float*)d_out;
    float* P   = (float*)d_ws;   // needs 196*32*768*4 = 19.3 MB

    int total = NPATCH * BATCH * PDIM;
    extract_patches_kernel<<<(total + 255) / 256, 256, 0, stream>>>(x, P);
    patch_gemm_kernel<<<NPATCH * 3, 256, 0, stream>>>(P, W, bias, out);
}